// Round 6
// baseline (174.212 us; speedup 1.0000x reference)
//
#include <hip/hip_runtime.h>

// Fused grouped-QKV GEMM: out[t,kv,g,d] = sum_e in[t,e]*W[e,kv,g,d] + bias
// M=64, K=4096, N=6144. fp32 in/out.
//
// R13: single-kernel, no split-k, no workspace. Ledger: R7=R8=R9=163+-1
// (gemm schedule-invariant, BW-bound on the 100.7MB W stream); R10: the
// 2x384MiB poison fills (~118us) are unconditional floor; R11: in-kernel
// cross-block fences cost per-block L2 writebacks (gemm 175us) -- never;
// R12 (161.5): partial-traffic cut returned only 1.2us (L2/L3 absorbs
// small hot buffers). Remaining levers = the second launch + its
// serialization tail. This round: 6144 = 256x24 -> grid 256 (1 block/CU),
// 24-col tiles, full K=4096/block, epilogue writes out=acc+bias directly.
//  - depth-3 W prefetch (4 rotating reg sets): ds_write(tile s+1) consumes
//    loads issued 2 tile-bodies earlier (~1200cy > 900cy HBM) -- covers
//    the 1-block/CU exposure.
//  - chunked XCD map nt=(bid&7)*32+(bid>>3): each XCD owns 768 contiguous
//    cols, so 96B row segments sharing a 128B line stay in one L2.
//  - 24-wide tile = 16-frag + half-used frag (l15>=8 lanes not stored);
//    MFMA waste irrelevant at 0.7% MfmaUtil. LDS stride 24 (16B-aligned),
//    ~4-way read conflicts accepted (LDS not the critical pipe).
// Wait structure unchanged from verified R9/R12: reg-staged W (per-load
// counted vmcnt), one lgkmcnt(0)+s_barrier per tile, cvt_pk A-pack.

#define N_COLS 6144
#define K_DIM  4096
#define Q_SZ   (64 * 4096)
#define K_OFF  Q_SZ
#define V_OFF  (Q_SZ + 64 * 1024)
#define NTW    24          // tile width (6144 = 256 * 24)
#define BK     128
#define TILES  32          // 4096/128
#define LDSROW 24          // floats per k-row: 96B, 16B-aligned

typedef __bf16 bf16x8 __attribute__((ext_vector_type(8)));
typedef float  f32x4  __attribute__((ext_vector_type(4)));

__device__ __forceinline__ int out_index(int t, int n) {
    const int kv = n / 768;
    const int g  = (n >> 7) % 6;
    const int d  = n & 127;
    if (g < 4)  return t * 4096 + kv * 512 + g * 128 + d;   // q
    if (g == 4) return K_OFF + t * 1024 + kv * 128 + d;     // k
    return V_OFF + t * 1024 + kv * 128 + d;                 // v
}

__global__ __launch_bounds__(256, 1)
void qkv_gemm(const float* __restrict__ in, const float* __restrict__ w,
              const float* __restrict__ bias, float* __restrict__ out) {
    // +16 pad: nfi=1 lanes l15>=8 over-read up to row*24+31 (garbage, unused)
    __shared__ float Ws[2][BK * LDSROW + 16];

    const int tid  = threadIdx.x;
    // chunked XCD map: XCD (bid&7) gets 32 consecutive n-tiles
    const int nt   = ((int)blockIdx.x & 7) * 32 + ((int)blockIdx.x >> 3);
    const int n0   = nt * NTW;
    const int wid  = tid >> 6;
    const int lane = tid & 63;
    const int l15  = lane & 15;
    const int kblk = lane >> 4;

    // W staging: tile = BK x 24 floats = 768 16B chunks; thread owns 3:
    // u = r*256 + tid -> row u/6, chunk u%6 (cols 4c..4c+3). Precompute.
    int srow[3], scc[3];
    #pragma unroll
    for (int r = 0; r < 3; ++r) {
        const int u = r * 256 + tid;
        srow[r] = u / 6;
        scc[r]  = u - srow[r] * 6;
    }

    f32x4 acc[2];
    acc[0] = (f32x4){0.f, 0.f, 0.f, 0.f};
    acc[1] = (f32x4){0.f, 0.f, 0.f, 0.f};

    f32x4 wreg[4][3];          // 4 rotating sets x 3 chunks (depth-3)
    float4 a[8];               // A: 32 k-floats for this lane's slice

    const float* wbase = w + n0;
    const float* abase = in + (size_t)(wid * 16 + l15) * K_DIM + kblk * 8;

    auto WLOAD = [&](int s, int set) {
        const float* p = wbase + (size_t)s * BK * N_COLS;
        #pragma unroll
        for (int r = 0; r < 3; ++r)
            wreg[set][r] =
                *(const f32x4*)(p + (size_t)srow[r] * N_COLS + scc[r] * 4);
    };
    auto DSWRITE = [&](int set, int buf) {
        #pragma unroll
        for (int r = 0; r < 3; ++r)
            *(f32x4*)&Ws[buf][srow[r] * LDSROW + scc[r] * 4] = wreg[set][r];
    };
    auto ALOAD = [&](int s) {
        const float* ap = abase + (size_t)s * BK;
        #pragma unroll
        for (int q = 0; q < 4; ++q) {
            a[2 * q]     = *(const float4*)(ap + q * 32);
            a[2 * q + 1] = *(const float4*)(ap + q * 32 + 4);
        }
    };

    // STEP(s, p=s&1, set=s&3), all compile-time at call sites:
    // pack A(s) -> issue WLOAD(s+3)/ALOAD(s+1) -> MFMA from Ws[p] ->
    // commit tile s+1 -> lgkmcnt(0) + barrier.
    auto STEP = [&](int s, int p, int set) {
        bf16x8 av[4];
        #pragma unroll
        for (int q = 0; q < 4; ++q) {
            av[q][0] = (__bf16)a[2*q].x;   av[q][1] = (__bf16)a[2*q].y;
            av[q][2] = (__bf16)a[2*q].z;   av[q][3] = (__bf16)a[2*q].w;
            av[q][4] = (__bf16)a[2*q+1].x; av[q][5] = (__bf16)a[2*q+1].y;
            av[q][6] = (__bf16)a[2*q+1].z; av[q][7] = (__bf16)a[2*q+1].w;
        }
        if (s + 3 < TILES) WLOAD(s + 3, (set + 3) & 3);  // 2-body cover
        if (s + 1 < TILES) ALOAD(s + 1);

        #pragma unroll
        for (int q = 0; q < 4; ++q) {
            #pragma unroll
            for (int nfi = 0; nfi < 2; ++nfi) {
                const int nb = nfi * 16 + l15;   // nfi=1,l15>=8: pad garbage
                bf16x8 bv;
                #pragma unroll
                for (int j = 0; j < 8; ++j)
                    bv[j] = (__bf16)Ws[p][(q * 32 + kblk * 8 + j) * LDSROW + nb];
                acc[nfi] = __builtin_amdgcn_mfma_f32_16x16x32_bf16(
                    av[q], bv, acc[nfi], 0, 0, 0);
            }
        }

        if (s + 1 < TILES) {
            DSWRITE((set + 1) & 3, p ^ 1);       // waits only WLOAD(s+1)
            asm volatile("s_waitcnt lgkmcnt(0)" ::: "memory");
            __builtin_amdgcn_s_barrier();
        }
    };

    // prologue: tiles 0..2 in flight, tile0 committed (one exposed latency)
    WLOAD(0, 0);
    ALOAD(0);
    WLOAD(1, 1);
    WLOAD(2, 2);
    DSWRITE(0, 0);             // auto vmcnt wait: only wreg[0]'s loads
    asm volatile("s_waitcnt lgkmcnt(0)" ::: "memory");
    __builtin_amdgcn_s_barrier();

    for (int ss = 0; ss < TILES; ss += 4) {
        STEP(ss + 0, 0, 0);
        STEP(ss + 1, 1, 1);
        STEP(ss + 2, 0, 2);
        STEP(ss + 3, 1, 3);
    }

    // epilogue: out = acc + bias. C/D col = l15 (n), row = kblk*4 + r;
    // wave wid owns rows wid*16..+15. nfi=1 valid only for l15<8.
    {
        const int n = n0 + l15;
        const float b0 = bias[n];
        #pragma unroll
        for (int r = 0; r < 4; ++r) {
            const int t = wid * 16 + kblk * 4 + r;
            out[out_index(t, n)] = acc[0][r] + b0;
        }
    }
    if (l15 < 8) {
        const int n = n0 + 16 + l15;
        const float b1 = bias[n];
        #pragma unroll
        for (int r = 0; r < 4; ++r) {
            const int t = wid * 16 + kblk * 4 + r;
            out[out_index(t, n)] = acc[1][r] + b1;
        }
    }
}

extern "C" void kernel_launch(void* const* d_in, const int* in_sizes, int n_in,
                              void* d_out, int out_size, void* d_ws, size_t ws_size,
                              hipStream_t stream) {
    const float* in   = (const float*)d_in[0];  // [64, 4096]
    const float* w    = (const float*)d_in[1];  // [4096, 8, 6, 128]
    const float* bias = (const float*)d_in[2];  // [8, 6, 128]
    float* out  = (float*)d_out;
    (void)d_ws; (void)ws_size;                  // workspace-free

    qkv_gemm<<<256, 256, 0, stream>>>(in, w, bias, out);
}

// Round 7
// 165.871 us; speedup vs baseline: 1.0503x; 1.0503x over previous
//
#include <hip/hip_runtime.h>

// Fused grouped-QKV GEMM: out[t,kv,g,d] = sum_e in[t,e]*W[e,kv,g,d] + bias
// M=64, K=4096, N=6144. fp32 in/out.
//
// R14: R12's verified kernel, occupancy-doubled. Ledger: R7=R8=R9=163+-1
// (schedule-invariant); R10: 2x384MiB poison fills (~112-118us) are
// unconditional floor; R11: never fence cross-block (per-block L2 wb);
// R12 (161.5us, best): traffic cuts mostly L2/L3-absorbed; R13 (1 blk/CU):
// gemm 62.7us, all pipes idle, FETCH 53.5MB<100.7MB -> the gemm is
// LATENCY-bound (TLP is the lever, W half-L3-resident). This round:
// identical tile code, but KSPLIT 4->8 (K=512/block), grid 1536 = 6
// blocks/CU, launch_bounds(256,6): 24 waves/CU (2x R12). VGPR 72 <= 80
// (6-wave cap), LDS 6x16KB=96KB. 32-col fp32 tile = exactly one 128B
// line -> XCD-interleaved n-tiles never split a line. Partials 12.6MB.

#define N_COLS 6144
#define K_DIM  4096
#define Q_SZ   (64 * 4096)
#define K_OFF  Q_SZ
#define V_OFF  (Q_SZ + 64 * 1024)
#define OUT_ELEMS 393216   // 64*6144
#define NT     192         // n-tiles of 32
#define KSPLIT 8           // 512 k per block -> 1536 blocks (6/CU, exact)
#define BK     64
#define TILES  8           // 512/64

typedef __bf16 bf16x8 __attribute__((ext_vector_type(8)));
typedef float  f32x4  __attribute__((ext_vector_type(4)));

__device__ __forceinline__ int out_index(int t, int n) {
    const int kv = n / 768;
    const int g  = (n >> 7) % 6;
    const int d  = n & 127;
    if (g < 4)  return t * 4096 + kv * 512 + g * 128 + d;   // q
    if (g == 4) return K_OFF + t * 1024 + kv * 128 + d;     // k
    return V_OFF + t * 1024 + kv * 128 + d;                 // v
}

__global__ __launch_bounds__(256, 6)
void qkv_gemm(const float* __restrict__ in, const float* __restrict__ w,
              float* __restrict__ part) {
    __shared__ float Ws[2][BK * 32];   // 2 x 8KB fp32 W-tile, [k][n] k-major

    const int tid  = threadIdx.x;
    const int nt   = blockIdx.x % NT;    // bid%8 = nt%8 (192%8==0): k-split
    const int kq   = blockIdx.x / NT;    // blocks of a column share an XCD
    const int n0   = nt * 32;
    const int k0   = kq * (BK * TILES);  // kq*512
    const int wid  = tid >> 6;
    const int lane = tid & 63;
    const int l15  = lane & 15;
    const int kblk = lane >> 4;

    // W staging: thread owns 2 16B chunks, r=0..1: row k = r*32 + (tid>>3),
    // chunk c = tid&7 (cols 4c..4c+3 of 32). Swizzle: LDS word
    // [k*32 + (m ^ (((k>>3)&1)<<4))] holds W[k][m]; ds_write applies it at
    // chunk granularity (c' = c ^ (((k>>3)&1)<<2)). Read side: frag rows
    // kblk*8..+7 (and +32) all have (row>>3)&1 == kblk&1, so col' =
    // nb ^ ((kblk&1)<<4): kblk {0,2} banks c, {1,3} banks c^16 ->
    // 2 lanes/bank (free, m136).
    const int t3 = tid >> 3;   // 0..31
    const int c  = tid & 7;

    f32x4 acc[2];
    acc[0] = (f32x4){0.f, 0.f, 0.f, 0.f};
    acc[1] = (f32x4){0.f, 0.f, 0.f, 0.f};

    f32x4 wreg[2][2];          // 2 sets x 2 chunks (depth-2 W prefetch)
    float4 a[4];               // A rows for this wave's m-frag, one k-step

    const float* wbase = w + (size_t)k0 * N_COLS + n0 + c * 4;
    const float* abase = in + (size_t)(wid * 16 + l15) * K_DIM + k0 + kblk * 8;

    auto WLOAD = [&](int s, int set) {
        const float* p = wbase + (size_t)s * BK * N_COLS;
        #pragma unroll
        for (int r = 0; r < 2; ++r)
            wreg[set][r] = *(const f32x4*)(p + (size_t)(r * 32 + t3) * N_COLS);
    };
    auto DSWRITE = [&](int set, int buf) {
        #pragma unroll
        for (int r = 0; r < 2; ++r) {
            const int k  = r * 32 + t3;
            const int cc = c ^ (((k >> 3) & 1) << 2);
            *(f32x4*)&Ws[buf][k * 32 + 4 * cc] = wreg[set][r];
        }
    };
    auto ALOAD = [&](int s) {
        const float* ap = abase + (size_t)s * BK;
        a[0] = *(const float4*)ap;            // half0: k  0..7  (kblk slice)
        a[1] = *(const float4*)(ap + 4);
        a[2] = *(const float4*)(ap + 32);     // half1: k 32..39 (kblk slice)
        a[3] = *(const float4*)(ap + 36);
    };

    // prologue: tile0 -> buf0 (one exposed latency), tile1 loads in flight
    WLOAD(0, 0);
    ALOAD(0);
    WLOAD(1, 1);
    DSWRITE(0, 0);             // auto vmcnt wait: only wreg[0]'s loads
    asm volatile("s_waitcnt lgkmcnt(0)" ::: "memory");
    __builtin_amdgcn_s_barrier();

    #pragma unroll
    for (int s = 0; s < TILES; ++s) {
        // 1. pack A(s): two k-halves; (__bf16) cast = HW RNE cvt_pk
        bf16x8 av[2];
        #pragma unroll
        for (int h = 0; h < 2; ++h) {
            av[h][0] = (__bf16)a[2*h].x;   av[h][1] = (__bf16)a[2*h].y;
            av[h][2] = (__bf16)a[2*h].z;   av[h][3] = (__bf16)a[2*h].w;
            av[h][4] = (__bf16)a[2*h+1].x; av[h][5] = (__bf16)a[2*h+1].y;
            av[h][6] = (__bf16)a[2*h+1].z; av[h][7] = (__bf16)a[2*h+1].w;
        }

        // 2. prefetch issues (stay in flight across the barrier below)
        if (s + 2 < TILES) WLOAD(s + 2, s & 1);
        if (s + 1 < TILES) ALOAD(s + 1);

        // 3. B-frags from Ws[s&1] + MFMA; every wave uses both n-frags
        #pragma unroll
        for (int h = 0; h < 2; ++h) {
            #pragma unroll
            for (int nfi = 0; nfi < 2; ++nfi) {
                const int nb   = nfi * 16 + l15;
                const int base = (h * 32 + kblk * 8) * 32 + (nb ^ ((kblk & 1) << 4));
                bf16x8 bv;
                #pragma unroll
                for (int j = 0; j < 8; ++j)
                    bv[j] = (__bf16)Ws[s & 1][base + j * 32];
                acc[nfi] = __builtin_amdgcn_mfma_f32_16x16x32_bf16(
                    av[h], bv, acc[nfi], 0, 0, 0);
            }
        }

        // 4/5. commit tile s+1 into the other buffer; one barrier per tile
        if (s + 1 < TILES) {
            DSWRITE((s + 1) & 1, (s + 1) & 1);  // waits only WLOAD(s+1)
            asm volatile("s_waitcnt lgkmcnt(0)" ::: "memory");
            __builtin_amdgcn_s_barrier();
        }
    }

    // partials: C/D col = l15 (n), row = kblk*4 + r; wave wid owns rows
    // wid*16..wid*16+15. Plain stores (keep L2-resident for the reducer).
    float* pb = part + (size_t)kq * OUT_ELEMS;
    #pragma unroll
    for (int nfi = 0; nfi < 2; ++nfi) {
        const int n = n0 + nfi * 16 + l15;
        #pragma unroll
        for (int r = 0; r < 4; ++r) {
            const int t = wid * 16 + kblk * 4 + r;
            pb[(size_t)t * N_COLS + n] = acc[nfi][r];
        }
    }
}

// sum KSPLIT partials + bias, scatter to q|k|v. Grid 384: nt = bid%192 so
// bid%8 = nt%8 -> same XCD as the gemm blocks that wrote column nt (L2 hits
// on surviving partial lines). Each block: half h = bid/192 of column nt.
__global__ __launch_bounds__(256)
void qkv_reduce(const float* __restrict__ part, const float* __restrict__ bias,
                float* __restrict__ out) {
    const int nt = blockIdx.x % NT;
    const int h  = blockIdx.x / NT;
    const int t  = h * 32 + (threadIdx.x >> 3);
    const int n  = nt * 32 + (threadIdx.x & 7) * 4;
    const size_t i = (size_t)t * N_COLS + n;
    f32x4 s = *(const f32x4*)(bias + n);
    #pragma unroll
    for (int kq = 0; kq < KSPLIT; ++kq)
        s += *(const f32x4*)(part + (size_t)kq * OUT_ELEMS + i);
    *(f32x4*)(out + out_index(t, n)) = s;   // 4-chunk never crosses d-block
}

extern "C" void kernel_launch(void* const* d_in, const int* in_sizes, int n_in,
                              void* d_out, int out_size, void* d_ws, size_t ws_size,
                              hipStream_t stream) {
    const float* in   = (const float*)d_in[0];  // [64, 4096]
    const float* w    = (const float*)d_in[1];  // [4096, 8, 6, 128]
    const float* bias = (const float*)d_in[2];  // [8, 6, 128]
    float* out  = (float*)d_out;
    float* part = (float*)d_ws;                 // 8 * 1.57MB = 12.6MB fp32

    qkv_gemm<<<NT * KSPLIT, 256, 0, stream>>>(in, w, part);
    qkv_reduce<<<NT * 2, 256, 0, stream>>>(part, bias, out);
}

// Round 8
// 160.048 us; speedup vs baseline: 1.0885x; 1.0364x over previous
//
#include <hip/hip_runtime.h>

// Fused grouped-QKV GEMM: out[t,kv,g,d] = sum_e in[t,e]*W[e,kv,g,d] + bias
// M=64, K=4096, N=6144. fp32 in/out.
//
// R15: bf16-pair LDS. Ledger: R7=R8=R9 (schedule null), R10/R11 (fusion/
// fence negative), R12=161.5 best (traffic ~eps), R13 (4 waves/CU: 62.7us
// latency-bound), R14 (24 waves/CU: no better than 12) -> TLP saturates at
// gemm~36us = 2.9TB/s while supply is ~6.8 -> DEMAND-limited. The invariant
// all rounds shared: B-frag = 32 ds_read_b32 + 32 v_cvt per wave-body
// (~15us LDS-pipe + ~3us VALU per CU) -- co-dominant with the W stream.
// Fix: convert W->bf16 at staging, store k-PAIRS per u32 word in a
// [pr=k/2][n] grid = MFMA operand encoding. B-frag = 4 ds_read_b32
// (u32x4 -> bf16x8 bit_cast, zero cvt); ds_write halves (1 b128/thread);
// LDS halves. Read swizzle: col ^ ((kblk&1)<<4) -> 2-way banks (free).
// Geometry/A-path/partials/reduce identical to verified R12 (NT=192,
// KSPLIT=4, 768 blocks = 3/CU, BK=64, depth-2 reg-staged prefetch).

#define N_COLS 6144
#define K_DIM  4096
#define Q_SZ   (64 * 4096)
#define K_OFF  Q_SZ
#define V_OFF  (Q_SZ + 64 * 1024)
#define OUT_ELEMS 393216   // 64*6144
#define NT     192         // n-tiles of 32
#define KSPLIT 4           // 1024 k per block -> 768 blocks (3/CU, exact)
#define BK     64
#define TILES  16          // 1024/64
#define NPR    32          // pair-rows per tile (BK/2)

typedef __bf16 bf16x2 __attribute__((ext_vector_type(2)));
typedef __bf16 bf16x8 __attribute__((ext_vector_type(8)));
typedef float  f32x4  __attribute__((ext_vector_type(4)));
typedef unsigned int u32x4 __attribute__((ext_vector_type(4)));

__device__ __forceinline__ int out_index(int t, int n) {
    const int kv = n / 768;
    const int g  = (n >> 7) % 6;
    const int d  = n & 127;
    if (g < 4)  return t * 4096 + kv * 512 + g * 128 + d;   // q
    if (g == 4) return K_OFF + t * 1024 + kv * 128 + d;     // k
    return V_OFF + t * 1024 + kv * 128 + d;                 // v
}

__device__ __forceinline__ unsigned pack_bf16(float lo, float hi) {
    bf16x2 p;
    p[0] = (__bf16)lo;     // k even -> low 16 bits (matches A-pack order)
    p[1] = (__bf16)hi;     // k odd  -> high 16 bits
    return __builtin_bit_cast(unsigned, p);
}

__global__ __launch_bounds__(256, 3)
void qkv_gemm(const float* __restrict__ in, const float* __restrict__ w,
              float* __restrict__ part) {
    // [pr][n] u32 grid: word (pr, n ^ ((pr>>2&1)<<4)) = bf16 pair of
    // W[k=2pr][n], W[k=2pr+1][n]. 2 x 4KB (halved vs fp32).
    __shared__ unsigned Ws[2][NPR * 32];

    const int tid  = threadIdx.x;
    const int nt   = blockIdx.x % NT;    // bid%8 = nt%8: k-split blocks of a
    const int kq   = blockIdx.x / NT;    // column share an XCD
    const int n0   = nt * 32;
    const int k0   = kq * (BK * TILES);  // kq*1024
    const int wid  = tid >> 6;
    const int lane = tid & 63;
    const int l15  = lane & 15;
    const int kblk = lane >> 4;

    // staging: thread owns pair-row pr = tid>>3 (0..31), chunk c = tid&7
    // (cols 4c..4c+3). Loads global rows k=2pr and 2pr+1, packs 4 u32,
    // one ds_write_b128 at word pr*32 + (4c ^ ((pr>>2&1)<<4)).
    const int pr = tid >> 3;
    const int c  = tid & 7;
    const int wcol = (c * 4) ^ (((pr >> 2) & 1) << 4);

    f32x4 acc[2];
    acc[0] = (f32x4){0.f, 0.f, 0.f, 0.f};
    acc[1] = (f32x4){0.f, 0.f, 0.f, 0.f};

    f32x4 wreg[2][2];          // 2 sets x {row 2pr, row 2pr+1} (depth-2)
    float4 a[4];               // A rows for this wave's m-frag, one k-step

    const float* wbase = w + ((size_t)k0 + pr * 2) * N_COLS + n0 + c * 4;
    const float* abase = in + (size_t)(wid * 16 + l15) * K_DIM + k0 + kblk * 8;

    // read-side swizzled cols for the two n-frags (uniform per thread):
    // (pr>>2)&1 == kblk&1 for all 4 pair-rows of a frag read.
    const int nbx0 = (0 * 16 + l15) ^ ((kblk & 1) << 4);
    const int nbx1 = (1 * 16 + l15) ^ ((kblk & 1) << 4);

    auto WLOAD = [&](int s, int set) {
        const float* p = wbase + (size_t)s * BK * N_COLS;
        wreg[set][0] = *(const f32x4*)p;             // k = 2pr
        wreg[set][1] = *(const f32x4*)(p + N_COLS);  // k = 2pr+1
    };
    auto DSWRITE = [&](int set, int buf) {
        u32x4 w4;
        #pragma unroll
        for (int i = 0; i < 4; ++i)
            w4[i] = pack_bf16(wreg[set][0][i], wreg[set][1][i]);
        *(u32x4*)&Ws[buf][pr * 32 + wcol] = w4;
    };
    auto ALOAD = [&](int s) {
        const float* ap = abase + (size_t)s * BK;
        a[0] = *(const float4*)ap;            // half0: k  0..7  (kblk slice)
        a[1] = *(const float4*)(ap + 4);
        a[2] = *(const float4*)(ap + 32);     // half1: k 32..39 (kblk slice)
        a[3] = *(const float4*)(ap + 36);
    };

    // prologue: tile0 -> buf0 (one exposed latency), tile1 loads in flight
    WLOAD(0, 0);
    ALOAD(0);
    WLOAD(1, 1);
    DSWRITE(0, 0);             // auto vmcnt wait: only wreg[0]'s loads
    asm volatile("s_waitcnt lgkmcnt(0)" ::: "memory");
    __builtin_amdgcn_s_barrier();

    #pragma unroll
    for (int s = 0; s < TILES; ++s) {
        // 1. pack A(s): two k-halves; (__bf16) cast = HW RNE cvt_pk
        bf16x8 av[2];
        #pragma unroll
        for (int h = 0; h < 2; ++h) {
            av[h][0] = (__bf16)a[2*h].x;   av[h][1] = (__bf16)a[2*h].y;
            av[h][2] = (__bf16)a[2*h].z;   av[h][3] = (__bf16)a[2*h].w;
            av[h][4] = (__bf16)a[2*h+1].x; av[h][5] = (__bf16)a[2*h+1].y;
            av[h][6] = (__bf16)a[2*h+1].z; av[h][7] = (__bf16)a[2*h+1].w;
        }

        // 2. prefetch issues (stay in flight across the barrier below)
        if (s + 2 < TILES) WLOAD(s + 2, s & 1);
        if (s + 1 < TILES) ALOAD(s + 1);

        // 3. B-frags: 4 ds_read_b32 each (pair-rows h*16+kblk*4+i), bit_cast
        //    to bf16x8 -- k ascending pairs match av ordering. No cvts.
        #pragma unroll
        for (int h = 0; h < 2; ++h) {
            const int prb = h * 16 + kblk * 4;
            #pragma unroll
            for (int nfi = 0; nfi < 2; ++nfi) {
                const int nbx = nfi ? nbx1 : nbx0;
                u32x4 bu;
                #pragma unroll
                for (int i = 0; i < 4; ++i)
                    bu[i] = Ws[s & 1][(prb + i) * 32 + nbx];
                acc[nfi] = __builtin_amdgcn_mfma_f32_16x16x32_bf16(
                    av[h], __builtin_bit_cast(bf16x8, bu), acc[nfi], 0, 0, 0);
            }
        }

        // 4/5. commit tile s+1 into the other buffer; one barrier per tile
        if (s + 1 < TILES) {
            DSWRITE((s + 1) & 1, (s + 1) & 1);  // waits only WLOAD(s+1)
            asm volatile("s_waitcnt lgkmcnt(0)" ::: "memory");
            __builtin_amdgcn_s_barrier();
        }
    }

    // partials: C/D col = l15 (n), row = kblk*4 + r; wave wid owns rows
    // wid*16..wid*16+15. Plain stores (keep L2-resident for the reducer).
    float* pb = part + (size_t)kq * OUT_ELEMS;
    #pragma unroll
    for (int nfi = 0; nfi < 2; ++nfi) {
        const int n = n0 + nfi * 16 + l15;
        #pragma unroll
        for (int r = 0; r < 4; ++r) {
            const int t = wid * 16 + kblk * 4 + r;
            pb[(size_t)t * N_COLS + n] = acc[nfi][r];
        }
    }
}

// sum KSPLIT partials + bias, scatter to q|k|v. Grid 384: nt = bid%192 so
// bid%8 = nt%8 -> same XCD as the gemm blocks that wrote column nt (L2 hits
// on surviving partial lines). Each block: half h = bid/192 of column nt.
__global__ __launch_bounds__(256)
void qkv_reduce(const float* __restrict__ part, const float* __restrict__ bias,
                float* __restrict__ out) {
    const int nt = blockIdx.x % NT;
    const int h  = blockIdx.x / NT;
    const int t  = h * 32 + (threadIdx.x >> 3);
    const int n  = nt * 32 + (threadIdx.x & 7) * 4;
    const size_t i = (size_t)t * N_COLS + n;
    f32x4 s = *(const f32x4*)(bias + n);
    #pragma unroll
    for (int kq = 0; kq < KSPLIT; ++kq)
        s += *(const f32x4*)(part + (size_t)kq * OUT_ELEMS + i);
    *(f32x4*)(out + out_index(t, n)) = s;   // 4-chunk never crosses d-block
}

extern "C" void kernel_launch(void* const* d_in, const int* in_sizes, int n_in,
                              void* d_out, int out_size, void* d_ws, size_t ws_size,
                              hipStream_t stream) {
    const float* in   = (const float*)d_in[0];  // [64, 4096]
    const float* w    = (const float*)d_in[1];  // [4096, 8, 6, 128]
    const float* bias = (const float*)d_in[2];  // [8, 6, 128]
    float* out  = (float*)d_out;
    float* part = (float*)d_ws;                 // 4 * 1.57MB = 6.3MB fp32

    qkv_gemm<<<NT * KSPLIT, 256, 0, stream>>>(in, w, part);
    qkv_reduce<<<NT * 2, 256, 0, stream>>>(part, bias, out);
}